// Round 17
// baseline (412.994 us; speedup 1.0000x reference)
//
#include <hip/hip_runtime.h>
#include <hip/hip_bf16.h>
#include <stdint.h>

// ---------------------------------------------------------------------------
// ChebConv with attention + per-(t,k) dropout, MI355X bf16 MFMA implementation
// out[b,t,u,o] = relu( sum_k M[t,k] @ x[b,t] @ Theta[k] )   (associativity)
// mask = threefry2x32 partitionable, key(42), bits = x0^x1   (verified R0)
// B=32 T=12 V=1000(pad 1024) F=O=64 K=3
//
// R17: K=3072 single GEMM (R12/R13-verified restructure; R12/R13 timing
// proves ws >= 226MB full path runs) x fragment-order zero-LDS operands
// (R11/R16-verified Mf; ytf = y_k in B-frag order) x full-chunk register
// ping-pong (R16 was latency-bound at 34%: loads consumed same-iteration).
// No stage-2 -> pacc[4][4]=64 AGPR only; two frag sets = 128 VGPR -> fits
// 2 waves/SIMD. K-loop: zero LDS, zero barriers; LOADF(next) always a full
// 310cy MFMA burst ahead of its BURST. ut-fastest XCD decode: 8 consecutive
// blocks share each 768KB B panel in L2.
// ws: Mf [36<<20] bf16 (75.5MB) | ytf [3][12][NR][1024] bf16 frag-order
//     (full NR=2048: 151MB; total 226.5MB; quarter fallback NR=512)
// ---------------------------------------------------------------------------

typedef __attribute__((ext_vector_type(8))) short short8;
typedef __attribute__((ext_vector_type(4))) float f32x4;

__device__ __forceinline__ ushort f2bf(float f) {
  __hip_bfloat16 h = __float2bfloat16(f);
  return *reinterpret_cast<ushort*>(&h);
}

__device__ __forceinline__ short8 cvt8(float4 a, float4 b) {
  short8 r;
  r[0] = (short)f2bf(a.x); r[1] = (short)f2bf(a.y);
  r[2] = (short)f2bf(a.z); r[3] = (short)f2bf(a.w);
  r[4] = (short)f2bf(b.x); r[5] = (short)f2bf(b.y);
  r[6] = (short)f2bf(b.z); r[7] = (short)f2bf(b.w);
  return r;
}

__device__ __forceinline__ void threefry2x32(uint32_t c0, uint32_t c1,
                                             uint32_t& o0, uint32_t& o1) {
  const uint32_t ks0 = 0u;
  const uint32_t ks1 = 42u;
  const uint32_t ks2 = ks0 ^ ks1 ^ 0x1BD11BDAu;
  uint32_t x0 = c0 + ks0;
  uint32_t x1 = c1 + ks1;
#define TFR(r) { x0 += x1; x1 = (x1 << (r)) | (x1 >> (32 - (r))); x1 ^= x0; }
  TFR(13) TFR(15) TFR(26) TFR(6)
  x0 += ks1; x1 += ks2 + 1u;
  TFR(17) TFR(29) TFR(16) TFR(24)
  x0 += ks2; x1 += ks0 + 2u;
  TFR(13) TFR(15) TFR(26) TFR(6)
  x0 += ks0; x1 += ks1 + 3u;
  TFR(17) TFR(29) TFR(16) TFR(24)
  x0 += ks1; x1 += ks2 + 4u;
  TFR(13) TFR(15) TFR(26) TFR(6)
  x0 += ks2; x1 += ks0 + 5u;
#undef TFR
  o0 = x0; o1 = x1;
}

// ---------------------------------------------------------------------------
// Kernel 1: build masked M (bf16) in MFMA-fragment order (R11/R16-verified).
// elem = (((tk*64+u16)*16+vc)*2+ks)*512 + lane*8 + j;
// u = u16*16+(lane&15), v = vc*64+ks*32+(lane>>4)*8+j.
// ---------------------------------------------------------------------------
__global__ void build_m(const float* __restrict__ Att,
                        const float* __restrict__ cheb,
                        ushort* __restrict__ Mf) {
  const uint32_t idx = blockIdx.x * 256u + threadIdx.x;
  const uint32_t j = idx & 7u;
  const uint32_t lane = (idx >> 3) & 63u;
  const uint32_t ks = (idx >> 9) & 1u;
  const uint32_t c = (idx >> 10) & 15u;
  const uint32_t u16 = (idx >> 14) & 63u;
  const uint32_t tk = idx >> 20;
  const uint32_t up = u16 * 16u + (lane & 15u);
  const uint32_t vp = c * 64u + ks * 32u + (lane >> 4) * 8u + j;
  float val = 0.f;
  if ((vp < 1000u) & (up < 1000u)) {
    const uint32_t flat = (tk * 1000u + up) * 1000u + vp;
    uint32_t o0, o1;
    threefry2x32(0u, flat, o0, o1);
    const uint32_t bits = o0 ^ o1;
    const float u = __uint_as_float((bits >> 9) | 0x3f800000u) - 1.0f;
    if (u < 0.4f) {
      val = cheb[(tk % 3u) * 1000000u + up * 1000u + vp] *
            Att[up * 1000u + vp] * 2.5f;
    }
  }
  Mf[idx] = f2bf(val);
}

// ---------------------------------------------------------------------------
// Kernel 2: build_yt -- y_k[b,t] = x[b,t] @ Theta_k (R13-verified math),
// stored in B-FRAGMENT order:
//   elem = ((((k*12+t)*NR16 + n16)*16 + vc)*2 + ks)*512 + lane*8 + j,
//   n = n16*16+(lane&15) = (b-bq0)*64+o,  v = vc*64+ks*32+(lane>>4)*8+j.
// 192 thr (3 waves), wave w <-> k=w; 8 vc per block.
// ---------------------------------------------------------------------------
#define MFMA(a, b, c) __builtin_amdgcn_mfma_f32_16x16x32_bf16((a), (b), (c), 0, 0, 0)

__global__ __launch_bounds__(192, 1)
void build_yt(const float* __restrict__ x, const float* __restrict__ Theta,
              ushort* __restrict__ ytf, int NR16, int bq0) {
  __shared__ __align__(16) ushort sm[27648];  // sTh [0,13824) | sY [13824,..)
  const int tid = threadIdx.x, lane = tid & 63, w = tid >> 6;
  const int quad = lane >> 4, l15 = lane & 15;
  const int vh = blockIdx.x, t = blockIdx.y, bb = blockIdx.z;
  const int b = bq0 + bb;

  for (int e = tid; e < 12288; e += 192) {
    const int k = e >> 12, rem = e & 4095, f = rem >> 6, o = rem & 63;
    sm[k * 4608 + o * 72 + f] = f2bf(Theta[e]);
  }
  __syncthreads();

  const ushort* sTh = sm + w * 4608;
  ushort* sY = sm + 13824 + w * 4608;
  const float* xb = x + (((size_t)b * 12 + t) * 1000) * 64;
  const int seg = lane & 7;

#pragma unroll 1
  for (int vi = 0; vi < 8; ++vi) {
    const int vc = vh * 8 + vi;
    const int v0 = vc * 64;

    f32x4 pacc[4][4];
#pragma unroll
    for (int i = 0; i < 4; ++i)
#pragma unroll
      for (int j = 0; j < 4; ++j) pacc[i][j] = f32x4{0.f, 0.f, 0.f, 0.f};

#pragma unroll
    for (int ks = 0; ks < 2; ++ks) {
      short8 av[4], bv[4];
#pragma unroll
      for (int mi = 0; mi < 4; ++mi)
        av[mi] = *(const short8*)&sTh[(mi * 16 + l15) * 72 + ks * 32 + quad * 8];
#pragma unroll
      for (int ni = 0; ni < 4; ++ni) {
        const int v = v0 + ni * 16 + l15;
        float4 c0 = make_float4(0.f, 0.f, 0.f, 0.f);
        float4 c1 = make_float4(0.f, 0.f, 0.f, 0.f);
        if (v < 1000) {
          const float* row = xb + (size_t)v * 64 + ks * 32 + quad * 8;
          c0 = *(const float4*)row;
          c1 = *(const float4*)(row + 4);
        }
        bv[ni] = cvt8(c0, c1);
      }
#pragma unroll
      for (int mi = 0; mi < 4; ++mi)
#pragma unroll
        for (int ni = 0; ni < 4; ++ni)
          pacc[mi][ni] = MFMA(av[mi], bv[ni], pacc[mi][ni]);
    }

    // wave-local transpose to sY[o][v-local]  (64x64, stride 72)
#pragma unroll
    for (int mi = 0; mi < 4; ++mi)
#pragma unroll
      for (int ni = 0; ni < 4; ++ni)
#pragma unroll
        for (int r = 0; r < 4; ++r)
          sY[(mi * 16 + quad * 4 + r) * 72 + ni * 16 + l15] = f2bf(pacc[mi][ni][r]);

    // fragment-order store: uint4 covers (o, v = v0+seg*8 .. +7)
#pragma unroll
    for (int p = 0; p < 8; ++p) {
      const int o = p * 8 + (lane >> 3);
      const uint4 val = *(const uint4*)&sY[o * 72 + seg * 8];
      const int n16 = bb * 4 + (o >> 4);
      const int lf = (o & 15) + 16 * (seg & 3);
      const int ks2 = seg >> 2;
      const size_t fb =
          ((((size_t)((w * 12 + t) * NR16 + n16) * 16 + vc) * 2 + ks2) << 9);
      *(uint4*)(ytf + fb + (size_t)lf * 8) = val;
    }
  }
}

// ---------------------------------------------------------------------------
// Kernel 3: K=3072 GEMM, zero-LDS zero-barrier, full-chunk reg ping-pong.
// 256 thr (4 waves, 2x2), block 128u x 128n per t, wave tile 64x64.
// 48 chunks of K=64 (chunk c: k-slab = c>>4, vc = c&15); per chunk per wave
// 8 A-frags + 8 B-frags (each one coalesced 1KB load) + 32 MFMA.
// pacc[4][4] = 64 AGPR; Pa/Pb/Qa/Qb = 128 VGPR -> ~218 unified, 2 waves/SIMD.
// Grid (full) 1536, XCD-bijective, ut-fastest (8 blocks share B panel in L2).
// ---------------------------------------------------------------------------
#define LOADF(AR, BR, C)                                                      \
  do {                                                                        \
    const size_t ko_ = (size_t)((C) >> 4);                                    \
    const size_t off_ = (size_t)((C) & 15) << 10;                             \
    const size_t aA_ = aBase + (ko_ << 20) + off_;                            \
    const size_t bA_ = bBase + ko_ * kslabB + off_;                           \
    _Pragma("unroll")                                                         \
    for (int mi = 0; mi < 4; ++mi)                                            \
      _Pragma("unroll")                                                       \
      for (int ks = 0; ks < 2; ++ks)                                          \
        AR[mi][ks] = *(const short8*)(Mf + aA_ + ((size_t)mi << 14) +         \
                                      ((size_t)ks << 9));                     \
    _Pragma("unroll")                                                         \
    for (int ni = 0; ni < 4; ++ni)                                            \
      _Pragma("unroll")                                                       \
      for (int ks = 0; ks < 2; ++ks)                                          \
        BR[ni][ks] = *(const short8*)(ytf + bA_ + ((size_t)ni << 14) +        \
                                      ((size_t)ks << 9));                     \
  } while (0)

#define BURST(AR, BR)                                                         \
  do {                                                                        \
    _Pragma("unroll")                                                         \
    for (int ks = 0; ks < 2; ++ks)                                            \
      _Pragma("unroll")                                                       \
      for (int mi = 0; mi < 4; ++mi)                                          \
        _Pragma("unroll")                                                     \
        for (int ni = 0; ni < 4; ++ni)                                        \
          pacc[mi][ni] = MFMA(AR[mi][ks], BR[ni][ks], pacc[mi][ni]);          \
  } while (0)

__global__ __launch_bounds__(256, 2)
void gemm_main(const ushort* __restrict__ Mf, const ushort* __restrict__ ytf,
               float* __restrict__ out, int NR16, int bq0, int ntcnt) {
  const int tid = threadIdx.x;
  const int lane = tid & 63;
  const int w = tid >> 6;              // wave 0..3
  const int wu = w >> 1, wn = w & 1;   // 2x2 wave grid, wave tile 64x64
  const int quad = lane >> 4, l15 = lane & 15;

  // XCD-bijective decode (gridDim.x % 8 == 0), ut-fastest per XCD chunk
  const int nb = (int)gridDim.x;
  const int swz = ((int)blockIdx.x & 7) * (nb >> 3) + ((int)blockIdx.x >> 3);
  const int ut = swz & 7;              // 8 u-tiles of 128
  const int g = swz >> 3;
  const int nt = g % ntcnt;
  const int t = g / ntcnt;
  const int u0 = ut * 128, n0 = nt * 128;

  // fragment base addresses (element offsets)
  const size_t aBase = ((size_t)(t * 192 + ut * 8 + wu * 4) << 14) +
                       (size_t)lane * 8;
  const size_t bBase = ((size_t)(t * NR16 + nt * 8 + wn * 4) << 14) +
                       (size_t)lane * 8;
  const size_t kslabB = (size_t)(12 * NR16) << 14;

  f32x4 pacc[4][4];
#pragma unroll
  for (int i = 0; i < 4; ++i)
#pragma unroll
    for (int j = 0; j < 4; ++j) pacc[i][j] = f32x4{0.f, 0.f, 0.f, 0.f};

  short8 Pa[4][2], Pb[4][2], Qa[4][2], Qb[4][2];

  // prologue
  LOADF(Pa, Pb, 0);

#pragma unroll 1
  for (int it = 0; it < 24; ++it) {
    LOADF(Qa, Qb, it * 2 + 1);           // in flight across BURST(P)
    __builtin_amdgcn_s_setprio(1);
    BURST(Pa, Pb);
    __builtin_amdgcn_s_setprio(0);
    if (it < 23) LOADF(Pa, Pb, it * 2 + 2);  // in flight across BURST(Q)
    __builtin_amdgcn_s_setprio(1);
    BURST(Qa, Qb);
    __builtin_amdgcn_s_setprio(0);
  }

  // epilogue: relu + f32 store
#pragma unroll
  for (int mi = 0; mi < 4; ++mi) {
    const int u_base = u0 + wu * 64 + mi * 16 + quad * 4;
#pragma unroll
    for (int ni = 0; ni < 4; ++ni) {
      const int n = n0 + wn * 64 + ni * 16 + l15;
      const int b = bq0 + (n >> 6), o = n & 63;
      float* op = out + (((size_t)b * 12 + t) * 1000) * 64 + o;
#pragma unroll
      for (int r = 0; r < 4; ++r) {
        const int u = u_base + r;
        if (u < 1000) op[(size_t)u * 64] = fmaxf(pacc[mi][ni][r], 0.f);
      }
    }
  }
}

// ---------------------------------------------------------------------------
extern "C" void kernel_launch(void* const* d_in, const int* in_sizes, int n_in,
                              void* d_out, int out_size, void* d_ws, size_t ws_size,
                              hipStream_t stream) {
  const float* x     = (const float*)d_in[0];
  const float* Att   = (const float*)d_in[1];
  const float* cheb  = (const float*)d_in[2];
  const float* Theta = (const float*)d_in[3];
  float* out = (float*)d_out;

  ushort* Mf  = (ushort*)d_ws;           // 75.5 MB fragment-ordered M
  ushort* ytf = Mf + 37748736ull;        // ytf region

  build_m<<<147456, 256, 0, stream>>>(Att, cheb, Mf);

  if (ws_size >= 226492416ull) {
    // full path: ytf [3][12][2048][1024] bf16 (151MB); NR16 = 2048/16 = 128
    build_yt<<<dim3(2, 12, 32), 192, 0, stream>>>(x, Theta, ytf, 128, 0);
    gemm_main<<<1536, 256, 0, stream>>>(Mf, ytf, out, 128, 0, 16);
  } else {
    // quarter path: 4 passes of 8 batches; ytf 37.7MB; NR16 = 512/16 = 32
    for (int qq = 0; qq < 4; ++qq) {
      build_yt<<<dim3(2, 12, 8), 192, 0, stream>>>(x, Theta, ytf, 32, qq * 8);
      gemm_main<<<384, 256, 0, stream>>>(Mf, ytf, out, 32, qq * 8, 4);
    }
  }
}

// Round 18
// 277.343 us; speedup vs baseline: 1.4891x; 1.4891x over previous
//
#include <hip/hip_runtime.h>
#include <hip/hip_bf16.h>
#include <stdint.h>

// ---------------------------------------------------------------------------
// ChebConv with attention + per-(t,k) dropout, MI355X bf16 MFMA implementation
// out[b,t,u,o] = relu( sum_k M[t,k] @ (x[b,t] @ Theta[k]) )
// mask = threefry2x32 partitionable, key(42), bits = x0^x1   (verified R0)
// B=32 T=12 V=1000(pad 1024) F=O=64 K=3
// ws: M row-major [36][1024][1024] bf16 (75.5MB) | xt [12][2048][1024] bf16
//
// R18: R15 (verified best, 205us, MfmaUtil 35%) + two structural fixes:
// (1) K-loop double-buffered LDS (2x40KB), ONE barrier per chunk -- writes
//     always target the buffer nobody reads this iteration. R15's single
//     buffer forced 2 barriers/chunk (stage<->read serialization).
// (2) prep fused into one kernel (transpose blocks first, VALU-bound build_m
//     back-fills the CUs) -- HBM pipe and VALU pipe overlap.
// R16/R17 (zero-LDS) proved the cache path (~56B/cy) can't feed MFMA;
// operands must flow through LDS (128B/cy). XOR content swizzle verified R3.
// ---------------------------------------------------------------------------

typedef __attribute__((ext_vector_type(8))) short short8;
typedef __attribute__((ext_vector_type(4))) float f32x4;

__device__ __forceinline__ ushort f2bf(float f) {
  __hip_bfloat16 h = __float2bfloat16(f);
  return *reinterpret_cast<ushort*>(&h);
}

__device__ __forceinline__ void threefry2x32(uint32_t c0, uint32_t c1,
                                             uint32_t& o0, uint32_t& o1) {
  const uint32_t ks0 = 0u;
  const uint32_t ks1 = 42u;
  const uint32_t ks2 = ks0 ^ ks1 ^ 0x1BD11BDAu;
  uint32_t x0 = c0 + ks0;
  uint32_t x1 = c1 + ks1;
#define TFR(r) { x0 += x1; x1 = (x1 << (r)) | (x1 >> (32 - (r))); x1 ^= x0; }
  TFR(13) TFR(15) TFR(26) TFR(6)
  x0 += ks1; x1 += ks2 + 1u;
  TFR(17) TFR(29) TFR(16) TFR(24)
  x0 += ks2; x1 += ks0 + 2u;
  TFR(13) TFR(15) TFR(26) TFR(6)
  x0 += ks0; x1 += ks1 + 3u;
  TFR(17) TFR(29) TFR(16) TFR(24)
  x0 += ks1; x1 += ks2 + 4u;
  TFR(13) TFR(15) TFR(26) TFR(6)
  x0 += ks2; x1 += ks0 + 5u;
#undef TFR
  o0 = x0; o1 = x1;
}

// ---------------------------------------------------------------------------
// Kernel 1 (fused prep): blocks [0,6144) = transpose_x, [6144,153600) =
// build_m. Transpose first so the HBM-bound role co-runs with VALU-bound
// mask generation as CUs free up.
// ---------------------------------------------------------------------------
__global__ void prep(const float* __restrict__ x,
                     const float* __restrict__ Att,
                     const float* __restrict__ cheb,
                     ushort* __restrict__ Mws,
                     ushort* __restrict__ xtw) {
  __shared__ float lt[64][65];
  const int bid = blockIdx.x;
  const int tid = threadIdx.x;

  if (bid >= 6144) {
    // ---- build_m role: masked M row-major [36][1024][1024] ----
    const uint32_t idx = (uint32_t)(bid - 6144) * 256u + tid;
    const uint32_t vp = idx & 1023u;
    const uint32_t up = (idx >> 10) & 1023u;
    const uint32_t tk = idx >> 20;
    float val = 0.f;
    if ((vp < 1000u) & (up < 1000u)) {
      const uint32_t flat = (tk * 1000u + up) * 1000u + vp;
      uint32_t o0, o1;
      threefry2x32(0u, flat, o0, o1);
      const uint32_t bits = o0 ^ o1;
      const float u = __uint_as_float((bits >> 9) | 0x3f800000u) - 1.0f;
      if (u < 0.4f) {
        val = cheb[(tk % 3u) * 1000000u + up * 1000u + vp] *
              Att[up * 1000u + vp] * 2.5f;
      }
    }
    Mws[idx] = f2bf(val);
    return;
  }

  // ---- transpose role: xt[t][n=b*64+f][v pad 1024] <- x[b][t][v][f] ----
  const int r = bid;
  const int vc = r & 15, t = (r >> 4) % 12, b = r / 192;
  const int v0 = vc * 64;
#pragma unroll
  for (int i = 0; i < 4; ++i) {
    const int c = i * 256 + tid;
    const int vi = c >> 4, f4 = c & 15;
    float4 q = make_float4(0.f, 0.f, 0.f, 0.f);
    if (v0 + vi < 1000)
      q = *(const float4*)(x + ((((size_t)b * 12 + t) * 1000 + v0 + vi) << 6) + f4 * 4);
    lt[f4 * 4 + 0][vi] = q.x;
    lt[f4 * 4 + 1][vi] = q.y;
    lt[f4 * 4 + 2][vi] = q.z;
    lt[f4 * 4 + 3][vi] = q.w;
  }
  __syncthreads();
  const int f = tid >> 2, g = tid & 3;
  alignas(16) ushort tmp[16];
#pragma unroll
  for (int j = 0; j < 16; ++j) tmp[j] = f2bf(lt[f][g * 16 + j]);
  const size_t base = ((size_t)(t * 2048 + b * 64 + f)) << 10;
  *(uint4*)(xtw + base + v0 + g * 16)     = *(const uint4*)&tmp[0];
  *(uint4*)(xtw + base + v0 + g * 16 + 8) = *(const uint4*)&tmp[8];
}

// ---------------------------------------------------------------------------
// Kernel 2: main fused GEMM.  256 thr (4 waves, 2x2), block 64u x 128n per t,
// wave tile 32u x 64n.  vc-outer (16 chunks of K=64), DOUBLE-BUFFERED LDS:
// buffer = sA 3x[64][64] + sB [128][64] = 40KB; two buffers = 80KB ->
// 2 blocks/CU (exactly 160KB).  One __syncthreads per chunk:
//   LOAD(vc+1 regs) -> BURST(buf[cur]) -> WRITE(regs -> buf[other]) -> sync.
// Write targets the buffer read LAST iteration (readers done at prev sync);
// reads of buf[cur] were written BEFORE prev sync.  B frags read once/wave,
// 48 MFMA into pacc[3] (AGPR).  Stage 2 (k unrolled, R15-verified):
// pacc[k] -> sP(bf16) -> oacc += P @ ThetaT[k].  Relu + f32 store.
// Content XOR-swizzle (verified R3): LDS[r][c16B] = G[r][c ^ (r&7)].
// Grid 3072 1D, XCD-bijective, ut-fastest (16 ut-blocks share xt panel L2).
// ---------------------------------------------------------------------------
#define LDT 72
#define MFMA(a, b, c) __builtin_amdgcn_mfma_f32_16x16x32_bf16((a), (b), (c), 0, 0, 0)

#define LOADCH(VC)                                                            \
  do {                                                                        \
    const size_t co_ = (size_t)(VC) * 64;                                     \
    p0 = *(const uint4*)(Mws + aS0 + co_);                                    \
    p1 = *(const uint4*)(Mws + aS1 + co_);                                    \
    p2 = *(const uint4*)(Mws + aS2 + co_);                                    \
    p3 = *(const uint4*)(Mws + aS3 + co_);                                    \
    p4 = *(const uint4*)(Mws + aS4 + co_);                                    \
    p5 = *(const uint4*)(Mws + aS5 + co_);                                    \
    p6 = *(const uint4*)(xt + bS0 + co_);                                     \
    p7 = *(const uint4*)(xt + bS1 + co_);                                     \
    p8 = *(const uint4*)(xt + bS2 + co_);                                     \
    p9 = *(const uint4*)(xt + bS3 + co_);                                     \
  } while (0)

#define WRITECH(BP)                                                           \
  do {                                                                        \
    *(uint4*)&(BP)[(tid) * 8]                = p0;                            \
    *(uint4*)&(BP)[(256 + tid) * 8]          = p1;                            \
    *(uint4*)&(BP)[(512 + tid) * 8]          = p2;                            \
    *(uint4*)&(BP)[(768 + tid) * 8]          = p3;                            \
    *(uint4*)&(BP)[(1024 + tid) * 8]         = p4;                            \
    *(uint4*)&(BP)[(1280 + tid) * 8]         = p5;                            \
    *(uint4*)&(BP)[12288 + (tid) * 8]        = p6;                            \
    *(uint4*)&(BP)[12288 + (256 + tid) * 8]  = p7;                            \
    *(uint4*)&(BP)[12288 + (512 + tid) * 8]  = p8;                            \
    *(uint4*)&(BP)[12288 + (768 + tid) * 8]  = p9;                            \
  } while (0)

#define BURST(BP)                                                             \
  do {                                                                        \
    _Pragma("unroll")                                                         \
    for (int ks = 0; ks < 2; ++ks) {                                          \
      const int cs_ = (((ks * 4 + quad) ^ rsw)) << 3;                         \
      short8 bv[4];                                                           \
      _Pragma("unroll")                                                       \
      for (int ni = 0; ni < 4; ++ni)                                          \
        bv[ni] = *(const short8*)&(BP)[12288 +                                \
                     (wn * 64 + ni * 16 + l15) * 64 + cs_];                   \
      _Pragma("unroll")                                                       \
      for (int k = 0; k < 3; ++k) {                                           \
        short8 av[2];                                                         \
        _Pragma("unroll")                                                     \
        for (int mi = 0; mi < 2; ++mi)                                        \
          av[mi] = *(const short8*)&(BP)[k * 4096 +                           \
                       (wu * 32 + mi * 16 + l15) * 64 + cs_];                 \
        _Pragma("unroll")                                                     \
        for (int mi = 0; mi < 2; ++mi)                                        \
          _Pragma("unroll")                                                   \
          for (int ni = 0; ni < 4; ++ni)                                      \
            pacc[k][mi][ni] = MFMA(av[mi], bv[ni], pacc[k][mi][ni]);          \
      }                                                                       \
    }                                                                         \
  } while (0)

__global__ __launch_bounds__(256, 2)
void cheb_main(const ushort* __restrict__ Mws, const ushort* __restrict__ xt,
               const float* __restrict__ Theta, float* __restrict__ out) {
  __shared__ __align__(16) ushort smem[40960];  // 80 KB: buf0 | buf1
  const int tid = threadIdx.x;
  const int lane = tid & 63;
  const int w = tid >> 6;              // wave 0..3
  const int wu = w >> 1, wn = w & 1;   // wave tile: u = wu*32, n = wn*64
  const int quad = lane >> 4, l15 = lane & 15;
  const int rsw = l15 & 7;

  ushort* buf0 = smem;
  ushort* buf1 = smem + 20480;

  // XCD-bijective decode (3072 % 8 == 0), ut-fastest within each XCD chunk
  const int bid = blockIdx.x;
  const int swz = (bid & 7) * 384 + (bid >> 3);
  const int ut = swz & 15;
  const int g = swz >> 4;              // 0..191
  const int nt = g & 15;
  const int t = g >> 4;                // 0..11
  const int u0 = ut * 64, n0 = nt * 128;

  const size_t mbase = (size_t)(t * 3) << 20;
  const size_t xrow0 = (size_t)(t * 2048 + n0);

  // staging source bases (content XOR pre-swizzle on 16B chunks) -- R15-verified
  const int rA0 = tid >> 3,              cA0 = (tid & 7) ^ (rA0 & 7);
  const int rA1 = ((256 + tid) >> 3) & 63, cA1 = (tid & 7) ^ (rA1 & 7);
  const size_t aS0 = mbase + ((size_t)(u0 + rA0) << 10) + cA0 * 8;
  const size_t aS1 = mbase + ((size_t)(u0 + rA1) << 10) + cA1 * 8;
  const size_t aS2 = mbase + (1ull << 20) + ((size_t)(u0 + rA0) << 10) + cA0 * 8;
  const size_t aS3 = mbase + (1ull << 20) + ((size_t)(u0 + rA1) << 10) + cA1 * 8;
  const size_t aS4 = mbase + (2ull << 20) + ((size_t)(u0 + rA0) << 10) + cA0 * 8;
  const size_t aS5 = mbase + (2ull << 20) + ((size_t)(u0 + rA1) << 10) + cA1 * 8;
  const int rB0 = tid >> 3,         cB0 = (tid & 7) ^ (rB0 & 7);
  const int rB1 = (256 + tid) >> 3, cB1 = (tid & 7) ^ (rB1 & 7);
  const int rB2 = (512 + tid) >> 3, cB2 = (tid & 7) ^ (rB2 & 7);
  const int rB3 = (768 + tid) >> 3, cB3 = (tid & 7) ^ (rB3 & 7);
  const size_t bS0 = ((xrow0 + rB0) << 10) + cB0 * 8;
  const size_t bS1 = ((xrow0 + rB1) << 10) + cB1 * 8;
  const size_t bS2 = ((xrow0 + rB2) << 10) + cB2 * 8;
  const size_t bS3 = ((xrow0 + rB3) << 10) + cB3 * 8;

  f32x4 pacc[3][2][4];
#pragma unroll
  for (int k = 0; k < 3; ++k)
#pragma unroll
    for (int i = 0; i < 2; ++i)
#pragma unroll
      for (int j = 0; j < 4; ++j) pacc[k][i][j] = f32x4{0.f, 0.f, 0.f, 0.f};

  uint4 p0, p1, p2, p3, p4, p5, p6, p7, p8, p9;

  // prologue: chunk 0 -> buf0
  LOADCH(0);
  WRITECH(buf0);
  __syncthreads();

  // main K loop: 16 chunks, unrolled x2 for static buffer pointers;
  // one barrier per chunk (write targets the buffer read last iteration)
#pragma unroll 1
  for (int it = 0; it < 8; ++it) {
    const int vc = it * 2;
    // even chunk: read buf0; prefetch vc+1 -> buf1
    if (vc < 15) LOADCH(vc + 1);
    __builtin_amdgcn_s_setprio(1);
    BURST(buf0);
    __builtin_amdgcn_s_setprio(0);
    if (vc < 15) WRITECH(buf1);
    __syncthreads();
    // odd chunk: read buf1; prefetch vc+2 -> buf0
    if (vc + 1 < 15) LOADCH(vc + 2);
    __builtin_amdgcn_s_setprio(1);
    BURST(buf1);
    __builtin_amdgcn_s_setprio(0);
    if (vc + 1 < 15) WRITECH(buf0);
    __syncthreads();
  }

  // ---- stage 2: oacc += P_k @ ThetaT[k], k fully unrolled (R15-verified) ----
  ushort* sP  = smem + w * 2304;       // 32 x 72, wave-local (buf0 overlay)
  ushort* sTh = smem + 9216;           // 64 x 72
  f32x4 oacc[2][4];
#pragma unroll
  for (int i = 0; i < 2; ++i)
#pragma unroll
    for (int j = 0; j < 4; ++j) oacc[i][j] = f32x4{0.f, 0.f, 0.f, 0.f};

#pragma unroll
  for (int k = 0; k < 3; ++k) {
    __syncthreads();  // prev readers done
#pragma unroll
    for (int mi = 0; mi < 2; ++mi)
#pragma unroll
      for (int ni = 0; ni < 4; ++ni)
#pragma unroll
        for (int r = 0; r < 4; ++r)
          sP[(mi * 16 + quad * 4 + r) * LDT + ni * 16 + l15] = f2bf(pacc[k][mi][ni][r]);
    for (int e = tid; e < 4096; e += 256) {
      const int f = e >> 6, o = e & 63;
      sTh[o * LDT + f] = f2bf(Theta[k * 4096 + e]);
    }
    __syncthreads();
#pragma unroll
    for (int ks = 0; ks < 2; ++ks) {
      short8 a2[2], b2[4];
#pragma unroll
      for (int mi = 0; mi < 2; ++mi)
        a2[mi] = *(const short8*)&sP[(mi * 16 + l15) * LDT + ks * 32 + quad * 8];
#pragma unroll
      for (int ni = 0; ni < 4; ++ni)
        b2[ni] = *(const short8*)&sTh[(ni * 16 + l15) * LDT + ks * 32 + quad * 8];
#pragma unroll
      for (int mi = 0; mi < 2; ++mi)
#pragma unroll
        for (int ni = 0; ni < 4; ++ni)
          oacc[mi][ni] = MFMA(a2[mi], b2[ni], oacc[mi][ni]);
    }
  }

  // ---- epilogue: relu + store ----
#pragma unroll
  for (int mi = 0; mi < 2; ++mi) {
    const int u_base = u0 + wu * 32 + mi * 16 + quad * 4;
#pragma unroll
    for (int ni = 0; ni < 4; ++ni) {
      const int n = n0 + wn * 64 + ni * 16 + l15;
      const int b = n >> 6, oo = n & 63;
      float* op = out + (((size_t)b * 12 + t) * 1000) * 64 + oo;
#pragma unroll
      for (int r = 0; r < 4; ++r) {
        const int u = u_base + r;
        if (u < 1000) op[(size_t)u * 64] = fmaxf(oacc[mi][ni][r], 0.f);
      }
    }
  }
}

// ---------------------------------------------------------------------------
extern "C" void kernel_launch(void* const* d_in, const int* in_sizes, int n_in,
                              void* d_out, int out_size, void* d_ws, size_t ws_size,
                              hipStream_t stream) {
  const float* x     = (const float*)d_in[0];
  const float* Att   = (const float*)d_in[1];
  const float* cheb  = (const float*)d_in[2];
  const float* Theta = (const float*)d_in[3];
  float* out = (float*)d_out;

  ushort* Mws = (ushort*)d_ws;                 // 36*1024*1024 bf16
  ushort* xtw = Mws + 37748736ull;             // 12*2048*1024 bf16
  // requires ws_size >= 125,829,120 bytes (proven budget)

  prep<<<153600, 256, 0, stream>>>(x, Att, cheb, Mws, xtw);
  cheb_main<<<3072, 256, 0, stream>>>(Mws, xtw, Theta, out);
}

// Round 19
// 272.475 us; speedup vs baseline: 1.5157x; 1.0179x over previous
//
#include <hip/hip_runtime.h>
#include <hip/hip_bf16.h>
#include <stdint.h>

// ---------------------------------------------------------------------------
// ChebConv with attention + per-(t,k) dropout, MI355X bf16 MFMA implementation
// out[b,t,u,o] = relu( sum_k M[t,k] @ (x[b,t] @ Theta[k]) )
// mask = threefry2x32 partitionable, key(42), bits = x0^x1   (verified R0)
// B=32 T=12 V=1000(pad 1024) F=O=64 K=3
// ws: Mf frag-order [36<<20] bf16 (75.5MB) | xt row-major [12][2048][1024]
//
// R19: HYBRID operand paths. R18's three pipes were all ~100% loaded
// (MFMA 1866cy, LDS 1875cy, global 1430cy per chunk-pair) -> any
// serialization inflates; measured 2.6x ideal. Fix: A (3 M-slabs, 60% of
// LDS traffic) moves OFF the LDS pipe -> R11/R16-verified fragment-order Mf,
// direct coalesced VGPR loads (L2-hot via ut-grouped XCD swizzle). B keeps
// R18's verified LDS dbuf (2x16KB, 1 barrier/chunk, XOR swizzle).
// New balance: LDS 750cy / global ~1200cy / MFMA 1866cy -> MFMA-bound.
// ---------------------------------------------------------------------------

typedef __attribute__((ext_vector_type(8))) short short8;
typedef __attribute__((ext_vector_type(4))) float f32x4;

__device__ __forceinline__ ushort f2bf(float f) {
  __hip_bfloat16 h = __float2bfloat16(f);
  return *reinterpret_cast<ushort*>(&h);
}

__device__ __forceinline__ void threefry2x32(uint32_t c0, uint32_t c1,
                                             uint32_t& o0, uint32_t& o1) {
  const uint32_t ks0 = 0u;
  const uint32_t ks1 = 42u;
  const uint32_t ks2 = ks0 ^ ks1 ^ 0x1BD11BDAu;
  uint32_t x0 = c0 + ks0;
  uint32_t x1 = c1 + ks1;
#define TFR(r) { x0 += x1; x1 = (x1 << (r)) | (x1 >> (32 - (r))); x1 ^= x0; }
  TFR(13) TFR(15) TFR(26) TFR(6)
  x0 += ks1; x1 += ks2 + 1u;
  TFR(17) TFR(29) TFR(16) TFR(24)
  x0 += ks2; x1 += ks0 + 2u;
  TFR(13) TFR(15) TFR(26) TFR(6)
  x0 += ks0; x1 += ks1 + 3u;
  TFR(17) TFR(29) TFR(16) TFR(24)
  x0 += ks1; x1 += ks2 + 4u;
  TFR(13) TFR(15) TFR(26) TFR(6)
  x0 += ks2; x1 += ks0 + 5u;
#undef TFR
  o0 = x0; o1 = x1;
}

// ---------------------------------------------------------------------------
// Kernel 1 (fused prep): blocks [0,6144) = transpose_x (HBM-bound),
// [6144,153600) = build_m in FRAGMENT order (VALU-bound) -- pipes overlap.
// Frag order (R11/R16-verified): elem = (((tk*64+u16)*16+vc)*2+ks)*512
//   + lane*8 + j;  u = u16*16+(lane&15), v = vc*64+ks*32+(lane>>4)*8+j.
// ---------------------------------------------------------------------------
__global__ void prep(const float* __restrict__ x,
                     const float* __restrict__ Att,
                     const float* __restrict__ cheb,
                     ushort* __restrict__ Mf,
                     ushort* __restrict__ xtw) {
  __shared__ float lt[64][65];
  const int bid = blockIdx.x;
  const int tid = threadIdx.x;

  if (bid >= 6144) {
    // ---- build_m role: masked M in MFMA-fragment order ----
    const uint32_t idx = (uint32_t)(bid - 6144) * 256u + tid;
    const uint32_t j = idx & 7u;
    const uint32_t lane = (idx >> 3) & 63u;
    const uint32_t ks = (idx >> 9) & 1u;
    const uint32_t c = (idx >> 10) & 15u;
    const uint32_t u16 = (idx >> 14) & 63u;
    const uint32_t tk = idx >> 20;
    const uint32_t up = u16 * 16u + (lane & 15u);
    const uint32_t vp = c * 64u + ks * 32u + (lane >> 4) * 8u + j;
    float val = 0.f;
    if ((vp < 1000u) & (up < 1000u)) {
      const uint32_t flat = (tk * 1000u + up) * 1000u + vp;
      uint32_t o0, o1;
      threefry2x32(0u, flat, o0, o1);
      const uint32_t bits = o0 ^ o1;
      const float u = __uint_as_float((bits >> 9) | 0x3f800000u) - 1.0f;
      if (u < 0.4f) {
        val = cheb[(tk % 3u) * 1000000u + up * 1000u + vp] *
              Att[up * 1000u + vp] * 2.5f;
      }
    }
    Mf[idx] = f2bf(val);
    return;
  }

  // ---- transpose role: xt[t][n=b*64+f][v pad 1024] <- x[b][t][v][f] ----
  const int r = bid;
  const int vc = r & 15, t = (r >> 4) % 12, b = r / 192;
  const int v0 = vc * 64;
#pragma unroll
  for (int i = 0; i < 4; ++i) {
    const int c = i * 256 + tid;
    const int vi = c >> 4, f4 = c & 15;
    float4 q = make_float4(0.f, 0.f, 0.f, 0.f);
    if (v0 + vi < 1000)
      q = *(const float4*)(x + ((((size_t)b * 12 + t) * 1000 + v0 + vi) << 6) + f4 * 4);
    lt[f4 * 4 + 0][vi] = q.x;
    lt[f4 * 4 + 1][vi] = q.y;
    lt[f4 * 4 + 2][vi] = q.z;
    lt[f4 * 4 + 3][vi] = q.w;
  }
  __syncthreads();
  const int f = tid >> 2, g = tid & 3;
  alignas(16) ushort tmp[16];
#pragma unroll
  for (int j = 0; j < 16; ++j) tmp[j] = f2bf(lt[f][g * 16 + j]);
  const size_t base = ((size_t)(t * 2048 + b * 64 + f)) << 10;
  *(uint4*)(xtw + base + v0 + g * 16)     = *(const uint4*)&tmp[0];
  *(uint4*)(xtw + base + v0 + g * 16 + 8) = *(const uint4*)&tmp[8];
}

// ---------------------------------------------------------------------------
// Kernel 2: main fused GEMM, hybrid operand paths.
// 256 thr (4 waves, 2x2), block 64u x 128n per t, wave tile 32u x 64n.
// Per 64-chunk: A = 12 frag loads direct from Mf (coalesced 1KB, L2-hot);
// B = LDS dbuf (2x16KB, one barrier/chunk, issue-early reg prefetch,
// XOR content swizzle verified R3). 48 MFMA into pacc[3] (AGPR).
// Stage 2 (k unrolled, R15-verified): pacc[k] -> sP -> oacc += P @ ThetaT[k].
// Grid 3072 1D, XCD-bijective, ut-fastest (A panels L2-hot per XCD).
// ---------------------------------------------------------------------------
#define LDT 72
#define MFMA(a, b, c) __builtin_amdgcn_mfma_f32_16x16x32_bf16((a), (b), (c), 0, 0, 0)

#define LOADB(VC)                                                             \
  do {                                                                        \
    const size_t co_ = (size_t)(VC) * 64;                                     \
    p6 = *(const uint4*)(xt + bS0 + co_);                                     \
    p7 = *(const uint4*)(xt + bS1 + co_);                                     \
    p8 = *(const uint4*)(xt + bS2 + co_);                                     \
    p9 = *(const uint4*)(xt + bS3 + co_);                                     \
  } while (0)

#define WRITEB(BP)                                                            \
  do {                                                                        \
    *(uint4*)&(BP)[(tid) * 8]        = p6;                                    \
    *(uint4*)&(BP)[(256 + tid) * 8]  = p7;                                    \
    *(uint4*)&(BP)[(512 + tid) * 8]  = p8;                                    \
    *(uint4*)&(BP)[(768 + tid) * 8]  = p9;                                    \
  } while (0)

#define LOADA(VC)                                                             \
  do {                                                                        \
    const size_t co_ = (size_t)(VC) << 10;                                    \
    _Pragma("unroll")                                                         \
    for (int k = 0; k < 3; ++k)                                               \
      _Pragma("unroll")                                                       \
      for (int mi = 0; mi < 2; ++mi)                                          \
        _Pragma("unroll")                                                     \
        for (int ks = 0; ks < 2; ++ks)                                        \
          a[k][mi][ks] = *(const short8*)(Mf + fA[k][mi] + co_ +              \
                                          ((size_t)ks << 9));                 \
  } while (0)

#define BURST(BP)                                                             \
  do {                                                                        \
    _Pragma("unroll")                                                         \
    for (int ks = 0; ks < 2; ++ks) {                                          \
      const int cs_ = (((ks * 4 + quad) ^ rsw)) << 3;                         \
      short8 bv[4];                                                           \
      _Pragma("unroll")                                                       \
      for (int ni = 0; ni < 4; ++ni)                                          \
        bv[ni] = *(const short8*)&(BP)[(wn * 64 + ni * 16 + l15) * 64 + cs_]; \
      _Pragma("unroll")                                                       \
      for (int k = 0; k < 3; ++k)                                             \
        _Pragma("unroll")                                                     \
        for (int mi = 0; mi < 2; ++mi)                                        \
          _Pragma("unroll")                                                   \
          for (int ni = 0; ni < 4; ++ni)                                      \
            pacc[k][mi][ni] = MFMA(a[k][mi][ks], bv[ni], pacc[k][mi][ni]);    \
    }                                                                         \
  } while (0)

__global__ __launch_bounds__(256, 2)
void cheb_main(const ushort* __restrict__ Mf, const ushort* __restrict__ xt,
               const float* __restrict__ Theta, float* __restrict__ out) {
  __shared__ __align__(16) ushort smem[16384];  // 32KB: B buf0 | buf1
  const int tid = threadIdx.x;
  const int lane = tid & 63;
  const int w = tid >> 6;              // wave 0..3
  const int wu = w >> 1, wn = w & 1;   // wave tile: u = wu*32, n = wn*64
  const int quad = lane >> 4, l15 = lane & 15;
  const int rsw = l15 & 7;

  ushort* buf0 = smem;
  ushort* buf1 = smem + 8192;

  // XCD-bijective decode (3072 % 8 == 0), ut-fastest within each XCD chunk
  const int bid = blockIdx.x;
  const int swz = (bid & 7) * 384 + (bid >> 3);
  const int ut = swz & 15;
  const int g = swz >> 4;              // 0..191
  const int nt = g & 15;
  const int t = g >> 4;                // 0..11
  const int u0 = ut * 64, n0 = nt * 128;

  // A fragment bases (frag-order Mf): u16 = ut*4 + wu*2 + mi
  size_t fA[3][2];
#pragma unroll
  for (int k = 0; k < 3; ++k)
#pragma unroll
    for (int mi = 0; mi < 2; ++mi)
      fA[k][mi] = (((size_t)((t * 3 + k) * 64 + ut * 4 + wu * 2 + mi)) << 14)
                  + (size_t)lane * 8;

  // B staging sources (xt row-major, XOR content pre-swizzle) -- R18-verified
  const size_t xrow0 = (size_t)(t * 2048 + n0);
  const int rB0 = tid >> 3,         cB0 = (tid & 7) ^ (rB0 & 7);
  const int rB1 = (256 + tid) >> 3, cB1 = (tid & 7) ^ (rB1 & 7);
  const int rB2 = (512 + tid) >> 3, cB2 = (tid & 7) ^ (rB2 & 7);
  const int rB3 = (768 + tid) >> 3, cB3 = (tid & 7) ^ (rB3 & 7);
  const size_t bS0 = ((xrow0 + rB0) << 10) + cB0 * 8;
  const size_t bS1 = ((xrow0 + rB1) << 10) + cB1 * 8;
  const size_t bS2 = ((xrow0 + rB2) << 10) + cB2 * 8;
  const size_t bS3 = ((xrow0 + rB3) << 10) + cB3 * 8;

  f32x4 pacc[3][2][4];
#pragma unroll
  for (int k = 0; k < 3; ++k)
#pragma unroll
    for (int i = 0; i < 2; ++i)
#pragma unroll
      for (int j = 0; j < 4; ++j) pacc[k][i][j] = f32x4{0.f, 0.f, 0.f, 0.f};

  short8 a[3][2][2];
  uint4 p6, p7, p8, p9;

  // prologue: B chunk 0 -> buf0
  LOADB(0);
  WRITEB(buf0);
  __syncthreads();

  // main K loop: 16 chunks, unrolled x2 for static buffer pointers;
  // one barrier per chunk (write targets buffer read last iteration)
#pragma unroll 1
  for (int it = 0; it < 8; ++it) {
    const int vc = it * 2;
    // even chunk: read buf0; prefetch B(vc+1) regs; A(vc) direct
    if (vc < 15) LOADB(vc + 1);
    LOADA(vc);
    __builtin_amdgcn_s_setprio(1);
    BURST(buf0);
    __builtin_amdgcn_s_setprio(0);
    if (vc < 15) WRITEB(buf1);
    __syncthreads();
    // odd chunk: read buf1; prefetch B(vc+2); A(vc+1)
    if (vc + 1 < 15) LOADB(vc + 2);
    LOADA(vc + 1);
    __builtin_amdgcn_s_setprio(1);
    BURST(buf1);
    __builtin_amdgcn_s_setprio(0);
    if (vc + 1 < 15) WRITEB(buf0);
    __syncthreads();
  }

  // ---- stage 2: oacc += P_k @ ThetaT[k], k fully unrolled (R15-verified) ----
  ushort* sP  = smem + w * 2304;       // 32 x 72, wave-local
  ushort* sTh = smem + 9216;           // 64 x 72  (9216+4608 = 13824 <= 16384)
  f32x4 oacc[2][4];
#pragma unroll
  for (int i = 0; i < 2; ++i)
#pragma unroll
    for (int j = 0; j < 4; ++j) oacc[i][j] = f32x4{0.f, 0.f, 0.f, 0.f};

#pragma unroll
  for (int k = 0; k < 3; ++k) {
    __syncthreads();  // prev readers done
#pragma unroll
    for (int mi = 0; mi < 2; ++mi)
#pragma unroll
      for (int ni = 0; ni < 4; ++ni)
#pragma unroll
        for (int r = 0; r < 4; ++r)
          sP[(mi * 16 + quad * 4 + r) * LDT + ni * 16 + l15] = f2bf(pacc[k][mi][ni][r]);
    for (int e = tid; e < 4096; e += 256) {
      const int f = e >> 6, o = e & 63;
      sTh[o * LDT + f] = f2bf(Theta[k * 4096 + e]);
    }
    __syncthreads();
#pragma unroll
    for (int ks = 0; ks < 2; ++ks) {
      short8 a2[2], b2[4];
#pragma unroll
      for (int mi = 0; mi < 2; ++mi)
        a2[mi] = *(const short8*)&sP[(mi * 16 + l15) * LDT + ks * 32 + quad * 8];
#pragma unroll
      for (int ni = 0; ni < 4; ++ni)
        b2[ni] = *(const short8*)&sTh[(ni * 16 + l15) * LDT + ks * 32 + quad * 8];
#pragma unroll
      for (int mi = 0; mi < 2; ++mi)
#pragma unroll
        for (int ni = 0; ni < 4; ++ni)
          oacc[mi][ni] = MFMA(a2[mi], b2[ni], oacc[mi][ni]);
    }
  }

  // ---- epilogue: relu + store ----
#pragma unroll
  for (int mi = 0; mi < 2; ++mi) {
    const int u_base = u0 + wu * 32 + mi * 16 + quad * 4;
#pragma unroll
    for (int ni = 0; ni < 4; ++ni) {
      const int n = n0 + wn * 64 + ni * 16 + l15;
      const int b = n >> 6, oo = n & 63;
      float* op = out + (((size_t)b * 12 + t) * 1000) * 64 + oo;
#pragma unroll
      for (int r = 0; r < 4; ++r) {
        const int u = u_base + r;
        if (u < 1000) op[(size_t)u * 64] = fmaxf(oacc[mi][ni][r], 0.f);
      }
    }
  }
}

// ---------------------------------------------------------------------------
extern "C" void kernel_launch(void* const* d_in, const int* in_sizes, int n_in,
                              void* d_out, int out_size, void* d_ws, size_t ws_size,
                              hipStream_t stream) {
  const float* x     = (const float*)d_in[0];
  const float* Att   = (const float*)d_in[1];
  const float* cheb  = (const float*)d_in[2];
  const float* Theta = (const float*)d_in[3];
  float* out = (float*)d_out;

  ushort* Mf  = (ushort*)d_ws;                 // 36*1024*1024 bf16, frag order
  ushort* xtw = Mf + 37748736ull;              // 12*2048*1024 bf16 row-major
  // requires ws_size >= 125,829,120 bytes (proven budget)

  prep<<<153600, 256, 0, stream>>>(x, Att, cheb, Mf, xtw);
  cheb_main<<<3072, 256, 0, stream>>>(Mf, xtw, Theta, out);
}